// Round 1
// baseline (477.962 us; speedup 1.0000x reference)
//
#include <hip/hip_runtime.h>
#include <math.h>

#define NTH 256
#define LSEQ 2048
#define NF 4096
#define NH 512
#define NS 64
#define NB 8

struct dc { double x, y; };
__device__ inline dc dadd(dc a, dc b){ return {a.x+b.x, a.y+b.y}; }
__device__ inline dc dsub(dc a, dc b){ return {a.x-b.x, a.y-b.y}; }
__device__ inline dc dmul(dc a, dc b){ return {a.x*b.x - a.y*b.y, a.x*b.y + a.y*b.x}; }
__device__ inline dc ddiv(dc a, dc b){
    double inv = 1.0/(b.x*b.x + b.y*b.y);
    return {(a.x*b.x + a.y*b.y)*inv, (a.y*b.x - a.x*b.y)*inv};
}

// In-place radix-2 DIT FFT over LDS. tw[j] = e^{-2*pi*i*j/n} (forward table).
// wsign=+1 -> forward DFT, wsign=-1 -> inverse (unnormalized).
__device__ inline void fft_lds(float2* s, const float2* tw, int log2n, float wsign) {
    const int n = 1 << log2n;
    const int tid = threadIdx.x;
    for (int i = tid; i < n; i += NTH) {
        unsigned j = __brev((unsigned)i) >> (32 - log2n);
        if ((int)j > i) { float2 t = s[i]; s[i] = s[j]; s[j] = t; }
    }
    __syncthreads();
    for (int st = 0; st < log2n; ++st) {
        const int mh = 1 << st;
        for (int k = tid; k < (n >> 1); k += NTH) {
            int pos = k & (mh - 1);
            int i0 = ((k >> st) << (st + 1)) | pos;
            int i1 = i0 + mh;
            float2 w = tw[pos << (log2n - 1 - st)];
            float wy = w.y * wsign;
            float2 a = s[i0], b = s[i1];
            float tr = w.x * b.x - wy * b.y;
            float ti = w.x * b.y + wy * b.x;
            s[i0] = make_float2(a.x + tr, a.y + ti);
            s[i1] = make_float2(a.x - tr, a.y - ti);
        }
        __syncthreads();
    }
}

// Phase 1: Cauchy resolvent sums (fp64) -> at_roots -> ifft -> K (H, L)
__global__ __launch_bounds__(NTH) void k_kernelK(
    const float* __restrict__ Lre, const float* __restrict__ Lim,
    const float* __restrict__ P, const float* __restrict__ B,
    const float* __restrict__ C, const float* __restrict__ logstep,
    float* __restrict__ Kout)
{
    __shared__ float2 s[LSEQ];
    __shared__ float2 tw[LSEQ/2];
    __shared__ dc lam[NS], ab00[NS], ab01[NS], ab10[NS], ab11[NS];
    const int h = blockIdx.x;
    const int tid = threadIdx.x;
    if (tid < NS) {
        int n = tid;
        int i = h * NS + n;
        double lr = fmin((double)Lre[i], -1e-4);
        double li = (double)Lim[i];
        lam[n] = {lr, li};
        dc Pc = {(double)P[2*i], (double)P[2*i+1]};
        dc Bc = {(double)B[2*i], (double)B[2*i+1]};
        dc Cc = {(double)C[2*i], (double)C[2*i+1]};
        dc a0 = {Cc.x, -Cc.y};   // conj(C)
        dc a1 = {Pc.x, -Pc.y};   // conj(P)
        ab00[n] = dmul(a0, Bc);
        ab01[n] = dmul(a0, Pc);
        ab10[n] = dmul(a1, Bc);
        ab11[n] = dmul(a1, Pc);
    }
    for (int j = tid; j < LSEQ/2; j += NTH) {
        double ang = 2.0 * M_PI * (double)j / (double)LSEQ;
        tw[j] = make_float2((float)cos(ang), (float)(-sin(ang)));
    }
    __syncthreads();
    const double step = exp((double)logstep[h]);
    const double two_over_step = 2.0 / step;
    for (int l = tid; l < LSEQ; l += NTH) {
        double th = -2.0 * M_PI * (double)l / (double)LSEQ;
        double cr = cos(th), ci = sin(th);
        dc onePlus = {1.0 + cr, ci};
        dc oneMinus = {1.0 - cr, -ci};
        dc num = {two_over_step * oneMinus.x, two_over_step * oneMinus.y};
        dc g = ddiv(num, onePlus);
        dc s00={0,0}, s01={0,0}, s10={0,0}, s11={0,0};
        for (int n = 0; n < NS; ++n) {
            dc d = dsub(g, lam[n]);
            double inv = 1.0 / (d.x*d.x + d.y*d.y);
            dc rec = {d.x*inv, -d.y*inv};
            s00 = dadd(s00, dmul(ab00[n], rec));
            s01 = dadd(s01, dmul(ab01[n], rec));
            s10 = dadd(s10, dmul(ab10[n], rec));
            s11 = dadd(s11, dmul(ab11[n], rec));
        }
        dc k = dsub(s00, ddiv(dmul(s01, s10), dadd({1.0,0.0}, s11)));
        dc cs = ddiv({2.0, 0.0}, onePlus);
        dc ar = dmul(cs, k);
        s[l] = make_float2((float)ar.x, (float)ar.y);
    }
    __syncthreads();
    fft_lds(s, tw, 11, -1.0f);             // inverse DFT (unnormalized)
    const float scale = 1.0f / (float)LSEQ;
    for (int t = tid; t < LSEQ; t += NTH)
        Kout[h * LSEQ + t] = s[t].x * scale;
}

// Phase 2: Kf = FFT_4096(zero-pad K) + D  (D*delta folded into spectrum)
__global__ __launch_bounds__(NTH) void k_kernelKf(
    const float* __restrict__ K, const float* __restrict__ D,
    float2* __restrict__ Kf)
{
    __shared__ float2 s[NF];
    __shared__ float2 tw[NF/2];
    const int h = blockIdx.x;
    const int tid = threadIdx.x;
    for (int t = tid; t < NF; t += NTH)
        s[t] = make_float2(t < LSEQ ? K[h*LSEQ + t] : 0.0f, 0.0f);
    for (int j = tid; j < NF/2; j += NTH) {
        double ang = 2.0 * M_PI * (double)j / (double)NF;
        tw[j] = make_float2((float)cos(ang), (float)(-sin(ang)));
    }
    __syncthreads();
    fft_lds(s, tw, 12, 1.0f);              // forward
    const float d = D[h];
    for (int k = tid; k < NF; k += NTH) {
        float2 v = s[k];
        v.x += d;
        Kf[(size_t)h * NF + k] = v;
    }
}

// Phase 3: per (b,h): FFT(u row) * Kf -> IFFT -> out (includes D*u via Kf)
__global__ __launch_bounds__(NTH) void k_conv(
    const float* __restrict__ u, const float2* __restrict__ Kf,
    float* __restrict__ out)
{
    __shared__ float2 s[NF];
    __shared__ float2 tw[NF/2];
    const int h = blockIdx.x;
    const int b = blockIdx.y;
    const int tid = threadIdx.x;
    const float* ub = u + (size_t)b * LSEQ * NH + h;
    for (int t = tid; t < NF; t += NTH)
        s[t] = make_float2(t < LSEQ ? ub[(size_t)t * NH] : 0.0f, 0.0f);
    for (int j = tid; j < NF/2; j += NTH) {
        double ang = 2.0 * M_PI * (double)j / (double)NF;
        tw[j] = make_float2((float)cos(ang), (float)(-sin(ang)));
    }
    __syncthreads();
    fft_lds(s, tw, 12, 1.0f);              // forward
    const float2* kf = Kf + (size_t)h * NF;
    for (int k = tid; k < NF; k += NTH) {
        float2 a = s[k], w = kf[k];
        s[k] = make_float2(a.x*w.x - a.y*w.y, a.x*w.y + a.y*w.x);
    }
    __syncthreads();
    fft_lds(s, tw, 12, -1.0f);             // inverse (unnormalized)
    const float scale = 1.0f / (float)NF;
    float* ob = out + (size_t)b * LSEQ * NH + h;
    for (int t = tid; t < LSEQ; t += NTH)
        ob[(size_t)t * NH] = s[t].x * scale;
}

extern "C" void kernel_launch(void* const* d_in, const int* in_sizes, int n_in,
                              void* d_out, int out_size, void* d_ws, size_t ws_size,
                              hipStream_t stream) {
    const float* u   = (const float*)d_in[0];
    const float* Lre = (const float*)d_in[1];
    const float* Lim = (const float*)d_in[2];
    const float* P   = (const float*)d_in[3];
    const float* B   = (const float*)d_in[4];
    const float* C   = (const float*)d_in[5];
    const float* D   = (const float*)d_in[6];
    const float* ls  = (const float*)d_in[7];
    float* out = (float*)d_out;

    float*  Kws = (float*)d_ws;                                          // 4 MB
    float2* Kf  = (float2*)((char*)d_ws + (size_t)NH * LSEQ * sizeof(float)); // 16 MB

    k_kernelK <<<NH, NTH, 0, stream>>>(Lre, Lim, P, B, C, ls, Kws);
    k_kernelKf<<<NH, NTH, 0, stream>>>(Kws, D, Kf);
    k_conv    <<<dim3(NH, NB), NTH, 0, stream>>>(u, Kf, out);
}

// Round 2
// 335.056 us; speedup vs baseline: 1.4265x; 1.4265x over previous
//
#include <hip/hip_runtime.h>
#include <math.h>

#define NTH 256
#define LSEQ 2048
#define NF 4096
#define NH 512
#define NS 64
#define NB 8
#define NPAIR (NH/2)          // 256 head pairs
#define TWN (NF - 1)          // 4095 packed twiddle entries (stages 0..11)

__device__ inline float2 cmul(float2 a, float2 b) {
    return make_float2(a.x*b.x - a.y*b.y, a.x*b.y + a.y*b.x);
}

// In-place radix-2 DIT FFT over LDS with PER-STAGE PACKED twiddles:
// twp[(1<<st)-1 + pos] = e^{-i*pi*pos/2^st}. Packed layout => consecutive
// lanes read consecutive entries => no LDS bank conflicts on twiddles.
// wsign=+1 forward, wsign=-1 inverse (unnormalized).
__device__ inline void fft_lds(float2* s, const float2* twp, int log2n, float wsign) {
    const int n = 1 << log2n;
    const int tid = threadIdx.x;
    for (int i = tid; i < n; i += NTH) {
        unsigned j = __brev((unsigned)i) >> (32 - log2n);
        if ((int)j > i) { float2 t = s[i]; s[i] = s[j]; s[j] = t; }
    }
    __syncthreads();
    for (int st = 0; st < log2n; ++st) {
        const int mh = 1 << st;
        const int base = mh - 1;
        for (int k = tid; k < (n >> 1); k += NTH) {
            int pos = k & (mh - 1);
            int i0 = ((k >> st) << (st + 1)) | pos;
            int i1 = i0 + mh;
            float2 w = twp[base + pos];
            float wy = w.y * wsign;
            float2 a = s[i0], b = s[i1];
            float tr = w.x * b.x - wy * b.y;
            float ti = w.x * b.y + wy * b.x;
            s[i0] = make_float2(a.x + tr, a.y + ti);
            s[i1] = make_float2(a.x - tr, a.y - ti);
        }
        __syncthreads();
    }
}

// One-time: packed twiddle table in fp64 precision.
// Entry e (1-based e+1 in [2^st, 2^{st+1})): pos = e+1-2^st, angle = -pi*pos/2^st.
// Note stage-11 subtable (entries 2047..4094) doubles as e^{-2*pi*i*t/4096}, t<2048.
__global__ void k_twinit(float2* __restrict__ twp) {
    int e = blockIdx.x * NTH + threadIdx.x;
    if (e < TWN) {
        int st = 31 - __clz(e + 1);
        int pos = (e + 1) - (1 << st);
        double ang = -3.14159265358979323846 * (double)pos / (double)(1 << st);
        twp[e] = make_float2((float)cos(ang), (float)sin(ang));
    }
}

// Phase 1+2 merged, fp32. Per head h:
//  g_l = i*(2/step)*tan(pi*l/L)  (pure imaginary!), c_scale_l = 1 + i*tan(pi*l/L)
//  at_roots -> Hermitian-symmetrize A -> even bins Kf[2j] = (A[j]+D)/4096
//  K = IFFT_2048(A).re ; modulate by e^{-2pi i t/4096}; FFT_2048 -> odd bins.
__global__ __launch_bounds__(NTH) void k_kern(
    const float* __restrict__ Lre, const float* __restrict__ Lim,
    const float* __restrict__ P, const float* __restrict__ B,
    const float* __restrict__ C, const float* __restrict__ Dp,
    const float* __restrict__ logstep, const float2* __restrict__ twp_g,
    float2* __restrict__ Kf)
{
    __shared__ float2 sA[LSEQ];
    __shared__ float2 twp[LSEQ - 1];
    __shared__ float2 lam[NS], ab00[NS], ab01[NS], ab10[NS], ab11[NS];
    __shared__ float2 S00tot;
    const int h = blockIdx.x;
    const int tid = threadIdx.x;
    for (int e = tid; e < LSEQ - 1; e += NTH) twp[e] = twp_g[e];
    if (tid < NS) {
        int i = h * NS + tid;
        lam[tid] = make_float2(fminf(Lre[i], -1e-4f), Lim[i]);
        float2 Pc = make_float2(P[2*i], P[2*i+1]);
        float2 Bc = make_float2(B[2*i], B[2*i+1]);
        float2 Cc = make_float2(C[2*i], C[2*i+1]);
        float2 a0 = make_float2(Cc.x, -Cc.y);
        float2 a1 = make_float2(Pc.x, -Pc.y);
        ab00[tid] = cmul(a0, Bc);
        ab01[tid] = cmul(a0, Pc);
        ab10[tid] = cmul(a1, Bc);
        ab11[tid] = cmul(a1, Pc);
    }
    __syncthreads();
    if (tid == 0) {
        float2 acc = make_float2(0.f, 0.f);
        for (int n = 0; n < NS; ++n) { acc.x += ab00[n].x; acc.y += ab00[n].y; }
        S00tot = acc;
    }
    __syncthreads();
    const float step = expf(logstep[h]);
    const float a2s = 2.0f / step;
    for (int l = tid; l < LSEQ; l += NTH) {
        float2 ar;
        if (l == LSEQ/2) {
            // t -> inf limit: c_scale*k -> (step/2)*sum(ab00)
            ar = make_float2(0.5f * step * S00tot.x, 0.5f * step * S00tot.y);
        } else {
            float r = (float)l * (1.0f / (float)LSEQ);
            float t = sinpif(r) / cospif(r);      // tan(pi*l/L), |t| <= ~1303
            float at = a2s * t;
            float2 s00 = make_float2(0,0), s01 = make_float2(0,0);
            float2 s10 = make_float2(0,0), s11 = make_float2(0,0);
            for (int n = 0; n < NS; ++n) {
                float dre = -lam[n].x;
                float dim = at - lam[n].y;
                float inv = 1.0f / (dre*dre + dim*dim);
                float2 rec = make_float2(dre * inv, -dim * inv);
                float2 c0 = ab00[n], c1 = ab01[n], c2 = ab10[n], c3 = ab11[n];
                s00.x += c0.x*rec.x - c0.y*rec.y; s00.y += c0.x*rec.y + c0.y*rec.x;
                s01.x += c1.x*rec.x - c1.y*rec.y; s01.y += c1.x*rec.y + c1.y*rec.x;
                s10.x += c2.x*rec.x - c2.y*rec.y; s10.y += c2.x*rec.y + c2.y*rec.x;
                s11.x += c3.x*rec.x - c3.y*rec.y; s11.y += c3.x*rec.y + c3.y*rec.x;
            }
            float2 den = make_float2(1.0f + s11.x, s11.y);
            float dinv = 1.0f / (den.x*den.x + den.y*den.y);
            float2 num = cmul(s01, s10);
            float2 q = make_float2((num.x*den.x + num.y*den.y) * dinv,
                                   (num.y*den.x - num.x*den.y) * dinv);
            float2 kk = make_float2(s00.x - q.x, s00.y - q.y);
            ar = make_float2(kk.x - t*kk.y, kk.y + t*kk.x);  // (1+i*t)*kk
        }
        sA[l] = ar;
    }
    __syncthreads();
    // Hermitian-symmetrize A[j] = (at[j] + conj(at[-j]))/2 ; write even bins.
    const float d = Dp[h];
    const float s4 = 1.0f / (float)NF;
    float2* KfH = Kf + (size_t)h * NF;
    for (int k = tid; k < LSEQ/2; k += NTH) {
        if (k == 0) {
            float A0 = sA[0].x, Am = sA[LSEQ/2].x;
            sA[0] = make_float2(A0, 0.f);
            sA[LSEQ/2] = make_float2(Am, 0.f);
            KfH[0]    = make_float2((A0 + d) * s4, 0.f);
            KfH[LSEQ] = make_float2((Am + d) * s4, 0.f);
        } else {
            int kn = LSEQ - k;
            float2 aa = sA[k], bb = sA[kn];
            float2 A  = make_float2(0.5f*(aa.x + bb.x), 0.5f*(aa.y - bb.y));
            float2 An = make_float2(0.5f*(bb.x + aa.x), 0.5f*(bb.y - aa.y));
            sA[k] = A; sA[kn] = An;
            KfH[2*k]  = make_float2((A.x + d) * s4,  A.y * s4);
            KfH[2*kn] = make_float2((An.x + d) * s4, An.y * s4);
        }
    }
    __syncthreads();
    fft_lds(sA, twp, 11, -1.0f);              // K*2048 (real in .x)
    const float s2 = 1.0f / (float)LSEQ;
    for (int t = tid; t < LSEQ; t += NTH) {
        float kv = sA[t].x * s2;
        float2 w = twp_g[(LSEQ - 1) + t];      // e^{-2*pi*i*t/4096}
        sA[t] = make_float2(kv * w.x, kv * w.y);
    }
    __syncthreads();
    fft_lds(sA, twp, 11, 1.0f);               // odd bins
    for (int j = tid; j < LSEQ; j += NTH) {
        float2 mj = sA[j];
        KfH[2*j + 1] = make_float2((mj.x + d) * s4, mj.y * s4);
    }
}

// Phase 3: one block per (b, head-pair). x[t] = u[2hp] + i*u[2hp+1];
// FFT; split via Hermitian symmetry; multiply by Kf rows; recombine; IFFT.
// Re -> out[2hp], Im -> out[2hp+1]. Scale & +D*u already folded into Kf.
__global__ __launch_bounds__(NTH) void k_conv(
    const float2* __restrict__ u2, const float2* __restrict__ Kf,
    const float2* __restrict__ twp_g, float2* __restrict__ out2)
{
    __shared__ float2 s[NF];
    __shared__ float2 twp[TWN];
    const int i = blockIdx.x;
    // XCD swizzle: blocks sharing 64B output lines (8 adjacent hp, same b)
    // land on the same XCD (hardware round-robins blockIdx % 8).
    const int x = i & 7;
    const int m = i >> 3;
    const int b = m >> 5;
    const int hp = x * 32 + (m & 31);
    const int tid = threadIdx.x;
    for (int e = tid; e < TWN; e += NTH) twp[e] = twp_g[e];
    const float2* ub = u2 + (size_t)b * LSEQ * NPAIR + hp;
    for (int t = tid; t < LSEQ; t += NTH) s[t] = ub[(size_t)t * NPAIR];
    for (int t = LSEQ + tid; t < NF; t += NTH) s[t] = make_float2(0.f, 0.f);
    __syncthreads();
    fft_lds(s, twp, 12, 1.0f);
    const float2* K0 = Kf + (size_t)(2*hp) * NF;
    const float2* K1 = K0 + NF;
    for (int k = tid; k < NF/2; k += NTH) {
        if (k == 0) {
            float2 X0 = s[0], Xm = s[NF/2];
            float2 g00 = K0[0], g10 = K1[0];
            float2 g0m = K0[NF/2], g1m = K1[NF/2];
            // U0 = Re(X), U1 = Im(X) at self-conjugate bins
            s[0] = make_float2(X0.x*g00.x - X0.y*g10.y, X0.x*g00.y + X0.y*g10.x);
            s[NF/2] = make_float2(Xm.x*g0m.x - Xm.y*g1m.y, Xm.x*g0m.y + Xm.y*g1m.x);
        } else {
            int kn = NF - k;
            float2 Xa = s[k], Xb = s[kn];
            float2 cb = make_float2(Xb.x, -Xb.y);
            float2 U0 = make_float2(0.5f*(Xa.x + cb.x), 0.5f*(Xa.y + cb.y));
            float2 df = make_float2(Xa.x - cb.x, Xa.y - cb.y);
            float2 U1 = make_float2(0.5f*df.y, -0.5f*df.x);   // -i/2 * df
            float2 U0c = make_float2(U0.x, -U0.y);            // U0[kn] = conj
            float2 U1c = make_float2(U1.x, -U1.y);
            float2 y0 = cmul(U0, K0[k]),  y1 = cmul(U1, K1[k]);
            s[k]  = make_float2(y0.x - y1.y, y0.y + y1.x);
            float2 z0 = cmul(U0c, K0[kn]), z1 = cmul(U1c, K1[kn]);
            s[kn] = make_float2(z0.x - z1.y, z0.y + z1.x);
        }
    }
    __syncthreads();
    fft_lds(s, twp, 12, -1.0f);
    float2* ob = out2 + (size_t)b * LSEQ * NPAIR + hp;
    for (int t = tid; t < LSEQ; t += NTH) ob[(size_t)t * NPAIR] = s[t];
}

extern "C" void kernel_launch(void* const* d_in, const int* in_sizes, int n_in,
                              void* d_out, int out_size, void* d_ws, size_t ws_size,
                              hipStream_t stream) {
    const float* u   = (const float*)d_in[0];
    const float* Lre = (const float*)d_in[1];
    const float* Lim = (const float*)d_in[2];
    const float* P   = (const float*)d_in[3];
    const float* B   = (const float*)d_in[4];
    const float* C   = (const float*)d_in[5];
    const float* D   = (const float*)d_in[6];
    const float* ls  = (const float*)d_in[7];
    float* out = (float*)d_out;

    float2* twp = (float2*)d_ws;                                   // 32 KB
    float2* Kf  = (float2*)((char*)d_ws + 65536);                  // 16 MB

    k_twinit<<<(TWN + NTH - 1) / NTH, NTH, 0, stream>>>(twp);
    k_kern  <<<NH, NTH, 0, stream>>>(Lre, Lim, P, B, C, D, ls, twp, Kf);
    k_conv  <<<NB * NPAIR, NTH, 0, stream>>>((const float2*)u, Kf, twp,
                                             (float2*)out);
}